// Round 14
// baseline (498.693 us; speedup 1.0000x reference)
//
#include <hip/hip_runtime.h>
#include <math.h>

#define N_NODES 100000
#define N_EDGES 1600000
#define DIM     128
#define NG      64
#define BN_EPS  1e-5f
#define NB      98       // scan blocks (1024 nodes each)
#define HRANGE  12500    // nodes per LDS range (50 KB)
#define NSLICE  32       // edge slices
#define ESLICE  (N_EDGES / NSLICE)   // 50000
#define NBLK_CONV 1563   // ceil(N_NODES/64)
#define SB      128      // rows per stats block
#define NSB     782      // ceil(N_NODES/SB)

typedef __attribute__((ext_vector_type(8))) short bf16x8;
typedef __attribute__((ext_vector_type(4))) float f32x4;

__device__ __forceinline__ unsigned short f2bf(float f) {
  unsigned b = __float_as_uint(f);
  unsigned r = (b + 0x7FFFu + ((b >> 16) & 1u)) >> 16;   // RNE
  return (unsigned short)r;
}

// ---------------------------------------------------------------- out-degree histogram (src), 256 blocks
__launch_bounds__(1024)
__global__ void k_histO(const int* __restrict__ src, int* __restrict__ cntO) {
  __shared__ int histo[HRANGE];
  int t = threadIdx.x;
  int range = blockIdx.x >> 5, blk = blockIdx.x & 31;
  int lo = range * HRANGE;
  for (int j = t; j < HRANGE; j += 1024) histo[j] = 0;
  __syncthreads();
  const int4* sp = (const int4*)(src + blk * ESLICE);
  for (int q = t; q < ESLICE / 4; q += 1024) {
    int4 v = sp[q];
    unsigned a = (unsigned)(v.x - lo), b = (unsigned)(v.y - lo);
    unsigned c = (unsigned)(v.z - lo), d = (unsigned)(v.w - lo);
    if (a < (unsigned)HRANGE) atomicAdd(&histo[a], 1);
    if (b < (unsigned)HRANGE) atomicAdd(&histo[b], 1);
    if (c < (unsigned)HRANGE) atomicAdd(&histo[c], 1);
    if (d < (unsigned)HRANGE) atomicAdd(&histo[d], 1);
  }
  __syncthreads();
  for (int j = t; j < HRANGE; j += 1024) {
    int v = histo[j];
    if (v) atomicAdd(&cntO[lo + j], v);
  }
}

// ---------------------------------------------------------------- in-degree per-slice histogram (dst), 256 blocks
__launch_bounds__(1024)
__global__ void k_histD(const int* __restrict__ dst, int* __restrict__ cnt_slice) {
  __shared__ int histo[HRANGE];
  int t = threadIdx.x;
  int range = blockIdx.x >> 5, slice = blockIdx.x & 31;
  int lo = range * HRANGE;
  for (int j = t; j < HRANGE; j += 1024) histo[j] = 0;
  __syncthreads();
  const int4* dp = (const int4*)(dst + slice * ESLICE);
  for (int q = t; q < ESLICE / 4; q += 1024) {
    int4 v = dp[q];
    unsigned a = (unsigned)(v.x - lo), b = (unsigned)(v.y - lo);
    unsigned c = (unsigned)(v.z - lo), d = (unsigned)(v.w - lo);
    if (a < (unsigned)HRANGE) atomicAdd(&histo[a], 1);
    if (b < (unsigned)HRANGE) atomicAdd(&histo[b], 1);
    if (c < (unsigned)HRANGE) atomicAdd(&histo[c], 1);
    if (d < (unsigned)HRANGE) atomicAdd(&histo[d], 1);
  }
  __syncthreads();
  for (int j = t; j < HRANGE; j += 1024)
    cnt_slice[(size_t)slice * N_NODES + lo + j] = histo[j];
}

// ---------------------------------------------------------------- scan pass 1 (+ fused slice exclusive-prefix)
__global__ void k_scan_part(int* __restrict__ cnt_slice, int* __restrict__ cnt,
                            int* __restrict__ bsum) {
  int b = blockIdx.x, t = threadIdx.x;
  int base = b * 1024 + t * 4;
  int tot = 0;
#pragma unroll
  for (int j = 0; j < 4; ++j) {
    int i = base + j;
    if (i < N_NODES) {
      int run = 0;
#pragma unroll
      for (int s = 0; s < NSLICE; ++s) {
        int v = cnt_slice[(size_t)s * N_NODES + i];
        cnt_slice[(size_t)s * N_NODES + i] = run;
        run += v;
      }
      cnt[i] = run;
      tot += run;
    }
  }
  __shared__ int red[256];
  red[t] = tot; __syncthreads();
  for (int w = 128; w; w >>= 1) { if (t < w) red[t] += red[t + w]; __syncthreads(); }
  if (t == 0) bsum[b] = red[0];
}

__global__ void k_scan_mid(const int* __restrict__ bsum, int* __restrict__ boff,
                           int* __restrict__ rowstart) {
  int t = threadIdx.x;
  __shared__ int sh[128];
  int own = (t < NB) ? bsum[t] : 0;
  sh[t] = own;
  __syncthreads();
  for (int off = 1; off < 128; off <<= 1) {
    int v = (t >= off) ? sh[t - off] : 0;
    __syncthreads();
    sh[t] += v;
    __syncthreads();
  }
  if (t < NB) boff[t] = sh[t] - own;
  if (t == NB - 1) rowstart[N_NODES] = sh[t];
}

__global__ void k_scan_fin(const int* __restrict__ cnt, const int* __restrict__ boff,
                           int* __restrict__ rowstart) {
  int b = blockIdx.x, t = threadIdx.x;
  int base = b * 1024 + t * 4;
  int v0 = 0, v1 = 0, v2 = 0, v3 = 0;
  if (base + 0 < N_NODES) v0 = cnt[base + 0];
  if (base + 1 < N_NODES) v1 = cnt[base + 1];
  if (base + 2 < N_NODES) v2 = cnt[base + 2];
  if (base + 3 < N_NODES) v3 = cnt[base + 3];
  int tsum = v0 + v1 + v2 + v3;
  __shared__ int sh[256];
  sh[t] = tsum;
  __syncthreads();
  for (int off = 1; off < 256; off <<= 1) {
    int v = (t >= off) ? sh[t - off] : 0;
    __syncthreads();
    sh[t] += v;
    __syncthreads();
  }
  int run = boff[b] + sh[t] - tsum;
  if (base + 0 < N_NODES) rowstart[base + 0] = run; run += v0;
  if (base + 1 < N_NODES) rowstart[base + 1] = run; run += v1;
  if (base + 2 < N_NODES) rowstart[base + 2] = run; run += v2;
  if (base + 3 < N_NODES) rowstart[base + 3] = run;
}

// ---------------------------------------------------------------- scatter via LDS cursor, 256 blocks
__launch_bounds__(1024)
__global__ void k_scatter_slice(const int* __restrict__ src, const int* __restrict__ dst,
                                const int* __restrict__ rowstart,
                                const int* __restrict__ cnt_slice, int* __restrict__ csr) {
  __shared__ int cur[HRANGE];
  int t = threadIdx.x;
  int range = blockIdx.x >> 5, slice = blockIdx.x & 31;
  int lo = range * HRANGE;
  for (int j = t; j < HRANGE; j += 1024)
    cur[j] = rowstart[lo + j] + cnt_slice[(size_t)slice * N_NODES + lo + j];
  __syncthreads();
  const int4* dp = (const int4*)(dst + slice * ESLICE);
  const int4* sp = (const int4*)(src + slice * ESLICE);
  for (int q = t; q < ESLICE / 4; q += 1024) {
    int4 d = dp[q];
    int4 s = sp[q];
    unsigned o;
    o = (unsigned)(d.x - lo); if (o < (unsigned)HRANGE) { int p = atomicAdd(&cur[o], 1); csr[p] = s.x; }
    o = (unsigned)(d.y - lo); if (o < (unsigned)HRANGE) { int p = atomicAdd(&cur[o], 1); csr[p] = s.y; }
    o = (unsigned)(d.z - lo); if (o < (unsigned)HRANGE) { int p = atomicAdd(&cur[o], 1); csr[p] = s.z; }
    o = (unsigned)(d.w - lo); if (o < (unsigned)HRANGE) { int p = atomicAdd(&cur[o], 1); csr[p] = s.w; }
  }
}

// ---------------------------------------------------------------- graph CSR starts
__global__ void k_starts_fill(const int* __restrict__ gid, int* __restrict__ starts) {
  int i = blockIdx.x * blockDim.x + threadIdx.x;
  if (i >= N_NODES) return;
  int gi = gid[i];
  if (i == 0) {
    for (int g = 0; g <= gi; ++g) starts[g] = 0;
  } else {
    int gp = gid[i - 1];
    if (gp != gi) for (int g = gp + 1; g <= gi; ++g) starts[g] = i;
  }
  if (i == N_NODES - 1) {
    for (int g = gi + 1; g <= NG; ++g) starts[g] = N_NODES;
  }
}

// ---------------------------------------------------------------- fused BN col stats + init_avg sums
__launch_bounds__(256)
__global__ void k_stats1(const float* __restrict__ x, const int* __restrict__ gid,
                         float* __restrict__ sums, float* __restrict__ initavg) {
  __shared__ float ls[8][DIM];
  __shared__ float ls2[8][DIM];
  __shared__ float lseg[4][8][DIM];
  int t = threadIdx.x;
  int col4 = (t & 31) * 4, rg = t >> 5;
  for (int i = t; i < 4 * 8 * DIM; i += 256) ((float*)lseg)[i] = 0.f;
  int base = blockIdx.x * SB;
  int rend = min(base + SB, N_NODES);
  int g0 = gid[base];
  int gl = gid[rend - 1];
  __syncthreads();
  float4 s = {0.f,0.f,0.f,0.f}, s2 = {0.f,0.f,0.f,0.f};
  float4 acc = {0.f,0.f,0.f,0.f};
  if (g0 == gl) {
    for (int r = base + rg; r < rend; r += 8) {
      float4 v = *(const float4*)&x[(size_t)r * DIM + col4];
      s.x += v.x; s.y += v.y; s.z += v.z; s.w += v.w;
      s2.x += v.x*v.x; s2.y += v.y*v.y; s2.z += v.z*v.z; s2.w += v.w*v.w;
      acc.x += v.x; acc.y += v.y; acc.z += v.z; acc.w += v.w;
    }
    lseg[0][rg][col4+0] = acc.x; lseg[0][rg][col4+1] = acc.y;
    lseg[0][rg][col4+2] = acc.z; lseg[0][rg][col4+3] = acc.w;
  } else {
    int curg = g0;
    for (int r = base + rg; r < rend; r += 8) {
      float4 v = *(const float4*)&x[(size_t)r * DIM + col4];
      s.x += v.x; s.y += v.y; s.z += v.z; s.w += v.w;
      s2.x += v.x*v.x; s2.y += v.y*v.y; s2.z += v.z*v.z; s2.w += v.w*v.w;
      int g = gid[r];
      if (g != curg) {
        int slot = curg - g0;
        if (slot < 4) {
          lseg[slot][rg][col4+0] = acc.x; lseg[slot][rg][col4+1] = acc.y;
          lseg[slot][rg][col4+2] = acc.z; lseg[slot][rg][col4+3] = acc.w;
        } else {
          atomicAdd(&initavg[curg * DIM + col4+0], acc.x);
          atomicAdd(&initavg[curg * DIM + col4+1], acc.y);
          atomicAdd(&initavg[curg * DIM + col4+2], acc.z);
          atomicAdd(&initavg[curg * DIM + col4+3], acc.w);
        }
        acc.x = acc.y = acc.z = acc.w = 0.f;
        curg = g;
      }
      acc.x += v.x; acc.y += v.y; acc.z += v.z; acc.w += v.w;
    }
    int slot = curg - g0;
    if (slot < 4) {
      lseg[slot][rg][col4+0] = acc.x; lseg[slot][rg][col4+1] = acc.y;
      lseg[slot][rg][col4+2] = acc.z; lseg[slot][rg][col4+3] = acc.w;
    } else {
      atomicAdd(&initavg[curg * DIM + col4+0], acc.x);
      atomicAdd(&initavg[curg * DIM + col4+1], acc.y);
      atomicAdd(&initavg[curg * DIM + col4+2], acc.z);
      atomicAdd(&initavg[curg * DIM + col4+3], acc.w);
    }
  }
  *(float4*)&ls[rg][col4] = s;
  *(float4*)&ls2[rg][col4] = s2;
  __syncthreads();
  if (t < DIM) {
    float a = 0.f, b = 0.f;
#pragma unroll
    for (int j = 0; j < 8; ++j) { a += ls[j][t]; b += ls2[j][t]; }
    atomicAdd(&sums[t], a);
    atomicAdd(&sums[DIM + t], b);
#pragma unroll
    for (int slot = 0; slot < 4; ++slot) {
      float v = 0.f;
#pragma unroll
      for (int j = 0; j < 8; ++j) v += lseg[slot][j][t];
      int g = g0 + slot;
      if (g < NG && v != 0.f) atomicAdd(&initavg[g * DIM + t], v);
    }
  }
}

__global__ void k_avg_div(const int* __restrict__ starts, float* __restrict__ outp) {
  int g = blockIdx.x, d = threadIdx.x;
  float cnt = fmaxf((float)(starts[g + 1] - starts[g]), 1.0f);
  outp[g * DIM + d] /= cnt;
}

// ---------------------------------------------------------------- layer-2 col sums from conv1 partials
__global__ void k_colred(const float* __restrict__ psum, const float* __restrict__ psq,
                         float* __restrict__ sums) {
  int c = blockIdx.x, t = threadIdx.x;
  __shared__ float r1[256], r2[256];
  float a = 0.f, b = 0.f;
  for (int j = t; j < NBLK_CONV; j += 256) {
    a += psum[(size_t)c * NBLK_CONV + j];
    b += psq[(size_t)c * NBLK_CONV + j];
  }
  r1[t] = a; r2[t] = b; __syncthreads();
  for (int w = 128; w; w >>= 1) { if (t < w) { r1[t] += r1[t + w]; r2[t] += r2[t + w]; } __syncthreads(); }
  if (t == 0) { sums[c] = r1[0]; sums[DIM + c] = r2[0]; }
}

// ---------------------------------------------------------------- xb = bf16(BN(x) * rsqrt(outdeg))
__launch_bounds__(256)
__global__ void k_bnx(const float* __restrict__ x, const float* __restrict__ sums,
                      const float* __restrict__ gamma, const float* __restrict__ beta,
                      const int* __restrict__ cntO, unsigned short* __restrict__ xb) {
  int idx = blockIdx.x * 256 + threadIdx.x;
  int row = idx >> 5, c4 = (idx & 31) * 4;
  float4 sm = *(const float4*)&sums[c4];
  float4 sq = *(const float4*)&sums[DIM + c4];
  float4 ga = *(const float4*)&gamma[c4];
  float4 be = *(const float4*)&beta[c4];
  const float inv = 1.0f / N_NODES;
  float4 sc, sh;
  {
    float m = sm.x * inv, va = sq.x * inv - m * m;
    sc.x = rsqrtf(fmaxf(va, 0.f) + BN_EPS) * ga.x; sh.x = be.x - m * sc.x;
    m = sm.y * inv; va = sq.y * inv - m * m;
    sc.y = rsqrtf(fmaxf(va, 0.f) + BN_EPS) * ga.y; sh.y = be.y - m * sc.y;
    m = sm.z * inv; va = sq.z * inv - m * m;
    sc.z = rsqrtf(fmaxf(va, 0.f) + BN_EPS) * ga.z; sh.z = be.z - m * sc.z;
    m = sm.w * inv; va = sq.w * inv - m * m;
    sc.w = rsqrtf(fmaxf(va, 0.f) + BN_EPS) * ga.w; sh.w = be.w - m * sc.w;
  }
  float4 v = *(const float4*)&x[(size_t)row * DIM + c4];
  float f = rsqrtf(fmaxf((float)cntO[row], 1.0f));
  ushort4 o;
  o.x = f2bf((v.x * sc.x + sh.x) * f);
  o.y = f2bf((v.y * sc.y + sh.y) * f);
  o.z = f2bf((v.z * sc.z + sh.z) * f);
  o.w = f2bf((v.w * sc.w + sh.w) * f);
  *(ushort4*)&xb[(size_t)row * DIM + c4] = o;
}

// ---------------------------------------------------------------- W -> bf16 transposed
__global__ void k_prepW(const float* __restrict__ W1, const float* __restrict__ W2,
                        unsigned short* __restrict__ WbT1, unsigned short* __restrict__ WbT2) {
  int idx = blockIdx.x * 256 + threadIdx.x;
  int which = idx >> 14;
  int i = idx & 16383;
  int k = i >> 7, c = i & 127;
  const float* W = which ? W2 : W1;
  unsigned short* O = which ? WbT2 : WbT1;
  O[c * DIM + k] = f2bf(W[k * DIM + c]);
}

// ---------------------------------------------------------------- FUSED SpMM + MFMA conv
// Each wave gathers 16 of the block's 64 rows straight into the As LDS tile (bf16),
// then the block does aggb@W + bias + relu + residual (+ gate, + column partials).
__launch_bounds__(256)
__global__ void k_spmmconv(const unsigned short* __restrict__ xb, const int* __restrict__ csr,
                           const int* __restrict__ rowstart,
                           const unsigned short* __restrict__ WbT,
                           const float* __restrict__ bias, const float* __restrict__ hres,
                           float* __restrict__ outp,
                           const float* __restrict__ gWp, const float* __restrict__ gbp,
                           float* __restrict__ gatep,
                           float* __restrict__ psum, float* __restrict__ psq) {
  __shared__ unsigned short As[64 * 136];    // 17408 B (stats scratch in epilogue)
  __shared__ unsigned short Ws[128 * 136];   // 34816 B (aliased as Of[64][132] f32)
  __shared__ float gsh[64];
  float* Of = (float*)Ws;
  int t = threadIdx.x;
  int row0 = blockIdx.x * 64;

  if (gatep && t < 64) gsh[t] = 0.f;

  // stage W^T while gathers are issued below (independent)
  for (int i = t; i < 2048; i += 256) {
    int c = i >> 4, q = i & 15;
    *(int4*)&Ws[c * 136 + q * 8] = *(const int4*)&WbT[(size_t)c * DIM + q * 8];
  }

  // gather: wave wid owns rows [wid*16, wid*16+16)
  int wid = t >> 6, l = t & 63;
  int half = l >> 5, l32 = l & 31;
  const size_t coff = (size_t)l32 * 4;
  for (int r = 0; r < 16; ++r) {
    int rl = wid * 16 + r;
    int row = row0 + rl;
    int s = 0, e = 0;
    if (row < N_NODES) { s = rowstart[row]; e = rowstart[row + 1]; }
    float4 acc = {0.f, 0.f, 0.f, 0.f};
    int i = s + half;
    for (; i + 6 < e; i += 8) {          // 4 neighbors per half per iter
      int s0 = csr[i], s1 = csr[i + 2], s2 = csr[i + 4], s3 = csr[i + 6];
      uint2 w0 = *(const uint2*)&xb[(size_t)s0 * DIM + coff];
      uint2 w1 = *(const uint2*)&xb[(size_t)s1 * DIM + coff];
      uint2 w2 = *(const uint2*)&xb[(size_t)s2 * DIM + coff];
      uint2 w3 = *(const uint2*)&xb[(size_t)s3 * DIM + coff];
      acc.x += __uint_as_float(w0.x << 16) + __uint_as_float(w1.x << 16)
             + __uint_as_float(w2.x << 16) + __uint_as_float(w3.x << 16);
      acc.y += __uint_as_float(w0.x & 0xFFFF0000u) + __uint_as_float(w1.x & 0xFFFF0000u)
             + __uint_as_float(w2.x & 0xFFFF0000u) + __uint_as_float(w3.x & 0xFFFF0000u);
      acc.z += __uint_as_float(w0.y << 16) + __uint_as_float(w1.y << 16)
             + __uint_as_float(w2.y << 16) + __uint_as_float(w3.y << 16);
      acc.w += __uint_as_float(w0.y & 0xFFFF0000u) + __uint_as_float(w1.y & 0xFFFF0000u)
             + __uint_as_float(w2.y & 0xFFFF0000u) + __uint_as_float(w3.y & 0xFFFF0000u);
    }
    for (; i < e; i += 2) {
      int s0 = csr[i];
      uint2 w0 = *(const uint2*)&xb[(size_t)s0 * DIM + coff];
      acc.x += __uint_as_float(w0.x << 16);
      acc.y += __uint_as_float(w0.x & 0xFFFF0000u);
      acc.z += __uint_as_float(w0.y << 16);
      acc.w += __uint_as_float(w0.y & 0xFFFF0000u);
    }
    acc.x += __shfl_xor(acc.x, 32);
    acc.y += __shfl_xor(acc.y, 32);
    acc.z += __shfl_xor(acc.z, 32);
    acc.w += __shfl_xor(acc.w, 32);
    if (half == 0) {
      float isi = rsqrtf(fmaxf((float)(e - s), 1.0f));
      ushort4 o;
      o.x = f2bf(acc.x * isi);
      o.y = f2bf(acc.y * isi);
      o.z = f2bf(acc.z * isi);
      o.w = f2bf(acc.w * isi);
      *(ushort4*)&As[rl * 136 + l32 * 4] = o;
    }
  }
  __syncthreads();

  // MFMA: 4 waves (2x2), 32x64 tile each, K=128
  int wr = wid >> 1, wc = wid & 1;
  int lr = l & 15, lq = l >> 4;
  f32x4 acc[2][4] = {};
  const unsigned short* Ab = &As[(wr * 32 + lr) * 136 + lq * 8];
  const unsigned short* Bb = &Ws[(wc * 64 + lr) * 136 + lq * 8];
#pragma unroll
  for (int kk = 0; kk < 4; ++kk) {
    bf16x8 a0 = *(const bf16x8*)(Ab + kk * 32);
    bf16x8 a1 = *(const bf16x8*)(Ab + 16 * 136 + kk * 32);
    bf16x8 b0 = *(const bf16x8*)(Bb + kk * 32);
    bf16x8 b1 = *(const bf16x8*)(Bb + 16 * 136 + kk * 32);
    bf16x8 b2 = *(const bf16x8*)(Bb + 32 * 136 + kk * 32);
    bf16x8 b3 = *(const bf16x8*)(Bb + 48 * 136 + kk * 32);
    acc[0][0] = __builtin_amdgcn_mfma_f32_16x16x32_bf16(a0, b0, acc[0][0], 0, 0, 0);
    acc[0][1] = __builtin_amdgcn_mfma_f32_16x16x32_bf16(a0, b1, acc[0][1], 0, 0, 0);
    acc[0][2] = __builtin_amdgcn_mfma_f32_16x16x32_bf16(a0, b2, acc[0][2], 0, 0, 0);
    acc[0][3] = __builtin_amdgcn_mfma_f32_16x16x32_bf16(a0, b3, acc[0][3], 0, 0, 0);
    acc[1][0] = __builtin_amdgcn_mfma_f32_16x16x32_bf16(a1, b0, acc[1][0], 0, 0, 0);
    acc[1][1] = __builtin_amdgcn_mfma_f32_16x16x32_bf16(a1, b1, acc[1][1], 0, 0, 0);
    acc[1][2] = __builtin_amdgcn_mfma_f32_16x16x32_bf16(a1, b2, acc[1][2], 0, 0, 0);
    acc[1][3] = __builtin_amdgcn_mfma_f32_16x16x32_bf16(a1, b3, acc[1][3], 0, 0, 0);
  }
  __syncthreads();

#pragma unroll
  for (int rt = 0; rt < 2; ++rt) {
#pragma unroll
    for (int ct = 0; ct < 4; ++ct) {
      int rr = wr * 32 + rt * 16 + lq * 4;
      int cc = wc * 64 + ct * 16 + lr;
#pragma unroll
      for (int i = 0; i < 4; ++i)
        Of[(rr + i) * 132 + cc] = acc[rt][ct][i];
    }
  }
  __syncthreads();

  float st[4] = {0.f, 0.f, 0.f, 0.f}, st2[4] = {0.f, 0.f, 0.f, 0.f};
#pragma unroll
  for (int i = 0; i < 8; ++i) {
    int fi = t + i * 256;
    int r = fi >> 5, c4 = (fi & 31) * 4;
    int row = row0 + r;
    if (row < N_NODES) {
      float4 o  = *(float4*)&Of[r * 132 + c4];
      float4 bv = *(const float4*)&bias[c4];
      float4 hv = *(const float4*)&hres[(size_t)row * DIM + c4];
      float4 y = {hv.x + fmaxf(o.x + bv.x, 0.f), hv.y + fmaxf(o.y + bv.y, 0.f),
                  hv.z + fmaxf(o.z + bv.z, 0.f), hv.w + fmaxf(o.w + bv.w, 0.f)};
      *(float4*)&outp[(size_t)row * DIM + c4] = y;
      if (gatep) {
        float4 gw = *(const float4*)&gWp[c4];
        atomicAdd(&gsh[r], y.x * gw.x + y.y * gw.y + y.z * gw.z + y.w * gw.w);
      }
      if (psum) {
        st[0] += y.x; st[1] += y.y; st[2] += y.z; st[3] += y.w;
        st2[0] += y.x*y.x; st2[1] += y.y*y.y; st2[2] += y.z*y.z; st2[3] += y.w*y.w;
      }
    }
  }
  if (gatep) {
    __syncthreads();
    int row = row0 + t;
    if (t < 64 && row < N_NODES) gatep[row] = gsh[t] + gbp[0];
  }
  if (psum) {
    float* sls  = (float*)As;
    float* sls2 = sls + 8 * DIM;
    int rg = t >> 5, c4 = (t & 31) * 4;
    __syncthreads();
#pragma unroll
    for (int i = 0; i < 4; ++i) {
      sls[rg * DIM + c4 + i]  = st[i];
      sls2[rg * DIM + c4 + i] = st2[i];
    }
    __syncthreads();
    if (t < DIM) {
      float a = 0.f, b = 0.f;
#pragma unroll
      for (int j = 0; j < 8; ++j) { a += sls[j * DIM + t]; b += sls2[j * DIM + t]; }
      psum[(size_t)t * NBLK_CONV + blockIdx.x] = a;
      psq[(size_t)t * NBLK_CONV + blockIdx.x]  = b;
    }
  }
}

// ---------------------------------------------------------------- per-graph softmax stats
__global__ void k_gstats(const float* __restrict__ gate, const int* __restrict__ starts,
                         float* __restrict__ gmax, float* __restrict__ gden) {
  int g = blockIdx.x;
  int s = starts[g], e = starts[g + 1];
  int t = threadIdx.x;
  __shared__ float red[256];
  float m = -INFINITY;
  for (int i = s + t; i < e; i += 256) m = fmaxf(m, gate[i]);
  red[t] = m; __syncthreads();
  for (int w = 128; w; w >>= 1) { if (t < w) red[t] = fmaxf(red[t], red[t + w]); __syncthreads(); }
  float mg = red[0]; __syncthreads();
  float ssum = 0.f;
  for (int i = s + t; i < e; i += 256) ssum += expf(gate[i] - mg);
  red[t] = ssum; __syncthreads();
  for (int w = 128; w; w >>= 1) { if (t < w) red[t] += red[t + w]; __syncthreads(); }
  if (t == 0) { gmax[g] = mg; gden[g] = red[0]; }
}

// ---------------------------------------------------------------- weighted pooling (2048 blocks, float4, LDS reduce)
__launch_bounds__(256)
__global__ void k_pool(const float* __restrict__ h2, const float* __restrict__ gate,
                       const int* __restrict__ starts, const float* __restrict__ gmax,
                       const float* __restrict__ gden, float* __restrict__ outp) {
  __shared__ float ls[8][DIM];
  int g = blockIdx.x >> 5, part = blockIdx.x & 31;
  int s = starts[g], e = starts[g + 1];
  int t = threadIdx.x;
  int col4 = (t & 31) * 4, rg = t >> 5;
  float mg = gmax[g];
  float dn = gden[g];
  float invden = dn > 0.f ? 1.0f / dn : 0.f;
  float4 acc = {0.f, 0.f, 0.f, 0.f};
  for (int i = s + part + rg * 32; i < e; i += 256) {
    float w = expf(gate[i] - mg) * invden;
    float4 v = *(const float4*)&h2[(size_t)i * DIM + col4];
    acc.x += w * v.x; acc.y += w * v.y; acc.z += w * v.z; acc.w += w * v.w;
  }
  *(float4*)&ls[rg][col4] = acc;
  __syncthreads();
  if (t < DIM) {
    float a = 0.f;
#pragma unroll
    for (int j = 0; j < 8; ++j) a += ls[j][t];
    if (a != 0.f) atomicAdd(&outp[g * DIM + t], a);
  }
}

// ---------------------------------------------------------------- launch
extern "C" void kernel_launch(void* const* d_in, const int* in_sizes, int n_in,
                              void* d_out, int out_size, void* d_ws, size_t ws_size,
                              hipStream_t stream) {
  const float* h    = (const float*)d_in[0];
  const int*   src  = (const int*)d_in[1];
  const int*   dst  = (const int*)d_in[2];
  const int*   gid  = (const int*)d_in[3];
  const float* W1   = (const float*)d_in[5];
  const float* b1   = (const float*)d_in[6];
  const float* W2   = (const float*)d_in[7];
  const float* b2   = (const float*)d_in[8];
  const float* gW   = (const float*)d_in[9];
  const float* gb   = (const float*)d_in[10];
  const float* gamma= (const float*)d_in[11];
  const float* beta = (const float*)d_in[12];
  float* out = (float*)d_out;

  char* ws = (char*)d_ws;
  float* h12     = (float*)ws; ws += (size_t)N_NODES * DIM * 4;
  unsigned short* xb   = (unsigned short*)ws; ws += (size_t)N_NODES * DIM * 2;
  int*   csr     = (int*)ws;   ws += (size_t)N_EDGES * 4;
  int*   cnt_slice = (int*)ws; ws += (size_t)NSLICE * N_NODES * 4;
  float* psum    = (float*)ws; ws += (size_t)DIM * NBLK_CONV * 4;
  float* psq     = (float*)ws; ws += (size_t)DIM * NBLK_CONV * 4;
  unsigned short* WbT1 = (unsigned short*)ws; ws += DIM * DIM * 2;
  unsigned short* WbT2 = (unsigned short*)ws; ws += DIM * DIM * 2;
  int*   rowstart= (int*)ws;   ws += (N_NODES + 1) * 4;
  int*   cnt     = (int*)ws;   ws += N_NODES * 4;
  int*   cntO    = (int*)ws;   ws += N_NODES * 4;
  float* gate    = (float*)ws; ws += N_NODES * 4;
  float* sums    = (float*)ws; ws += 2 * DIM * 4;
  float* gmax    = (float*)ws; ws += NG * 4;
  float* gden    = (float*)ws; ws += NG * 4;
  int*   starts  = (int*)ws;   ws += (NG + 1) * 4;
  int*   bsum    = (int*)ws;   ws += NB * 4;
  int*   boff    = (int*)ws;   ws += NB * 4;

  hipMemsetAsync(cntO,  0, N_NODES * 4, stream);
  hipMemsetAsync(sums,  0, 2 * DIM * 4, stream);
  hipMemsetAsync(d_out, 0, (size_t)out_size * 4, stream);

  // graph structure
  k_histO<<<256, 1024, 0, stream>>>(src, cntO);
  k_histD<<<256, 1024, 0, stream>>>(dst, cnt_slice);
  k_scan_part<<<NB, 256, 0, stream>>>(cnt_slice, cnt, bsum);
  k_scan_mid<<<1, 128, 0, stream>>>(bsum, boff, rowstart);
  k_scan_fin<<<NB, 256, 0, stream>>>(cnt, boff, rowstart);
  k_scatter_slice<<<256, 1024, 0, stream>>>(src, dst, rowstart, cnt_slice, csr);
  k_starts_fill<<<(N_NODES + 255) / 256, 256, 0, stream>>>(gid, starts);
  k_prepW<<<128, 256, 0, stream>>>(W1, W2, WbT1, WbT2);

  // layer 1 (stats fused with init_avg accumulation)
  k_stats1<<<NSB, 256, 0, stream>>>(h, gid, sums, out + NG * DIM);
  k_avg_div<<<NG, DIM, 0, stream>>>(starts, out + NG * DIM);
  k_bnx<<<N_NODES * 32 / 256, 256, 0, stream>>>(h, sums, gamma, beta, cntO, xb);
  k_spmmconv<<<NBLK_CONV, 256, 0, stream>>>(xb, csr, rowstart, WbT1, b1, h, h12,
                                            nullptr, nullptr, nullptr, psum, psq);

  // layer 2 (stats from conv1 partials)
  k_colred<<<DIM, 256, 0, stream>>>(psum, psq, sums);
  k_bnx<<<N_NODES * 32 / 256, 256, 0, stream>>>(h12, sums, gamma, beta, cntO, xb);
  k_spmmconv<<<NBLK_CONV, 256, 0, stream>>>(xb, csr, rowstart, WbT2, b2, h12, h12,
                                            gW, gb, gate, nullptr, nullptr);

  // pooling
  k_gstats<<<NG, 256, 0, stream>>>(gate, starts, gmax, gden);
  k_pool<<<NG * 32, 256, 0, stream>>>(h12, gate, starts, gmax, gden, out);
}

// Round 15
// 370.499 us; speedup vs baseline: 1.3460x; 1.3460x over previous
//
#include <hip/hip_runtime.h>
#include <math.h>

#define N_NODES 100000
#define N_EDGES 1600000
#define DIM     128
#define NG      64
#define BN_EPS  1e-5f
#define NB      98       // scan blocks (1024 nodes each)
#define HRANGE  12500    // nodes per LDS range (50 KB)
#define NSLICE  32       // edge slices
#define ESLICE  (N_EDGES / NSLICE)   // 50000
#define NBLK_CONV 1563   // ceil(N_NODES/64)
#define SB      128      // rows per stats block
#define NSB     782      // ceil(N_NODES/SB)

typedef __attribute__((ext_vector_type(8))) short bf16x8;
typedef __attribute__((ext_vector_type(4))) float f32x4;

__device__ __forceinline__ unsigned short f2bf(float f) {
  unsigned b = __float_as_uint(f);
  unsigned r = (b + 0x7FFFu + ((b >> 16) & 1u)) >> 16;   // RNE
  return (unsigned short)r;
}

// ---------------------------------------------------------------- out-degree histogram (src), 256 blocks
__launch_bounds__(1024)
__global__ void k_histO(const int* __restrict__ src, int* __restrict__ cntO) {
  __shared__ int histo[HRANGE];
  int t = threadIdx.x;
  int range = blockIdx.x >> 5, blk = blockIdx.x & 31;
  int lo = range * HRANGE;
  for (int j = t; j < HRANGE; j += 1024) histo[j] = 0;
  __syncthreads();
  const int4* sp = (const int4*)(src + blk * ESLICE);
  for (int q = t; q < ESLICE / 4; q += 1024) {
    int4 v = sp[q];
    unsigned a = (unsigned)(v.x - lo), b = (unsigned)(v.y - lo);
    unsigned c = (unsigned)(v.z - lo), d = (unsigned)(v.w - lo);
    if (a < (unsigned)HRANGE) atomicAdd(&histo[a], 1);
    if (b < (unsigned)HRANGE) atomicAdd(&histo[b], 1);
    if (c < (unsigned)HRANGE) atomicAdd(&histo[c], 1);
    if (d < (unsigned)HRANGE) atomicAdd(&histo[d], 1);
  }
  __syncthreads();
  for (int j = t; j < HRANGE; j += 1024) {
    int v = histo[j];
    if (v) atomicAdd(&cntO[lo + j], v);
  }
}

// ---------------------------------------------------------------- in-degree per-slice histogram (dst), 256 blocks
__launch_bounds__(1024)
__global__ void k_histD(const int* __restrict__ dst, int* __restrict__ cnt_slice) {
  __shared__ int histo[HRANGE];
  int t = threadIdx.x;
  int range = blockIdx.x >> 5, slice = blockIdx.x & 31;
  int lo = range * HRANGE;
  for (int j = t; j < HRANGE; j += 1024) histo[j] = 0;
  __syncthreads();
  const int4* dp = (const int4*)(dst + slice * ESLICE);
  for (int q = t; q < ESLICE / 4; q += 1024) {
    int4 v = dp[q];
    unsigned a = (unsigned)(v.x - lo), b = (unsigned)(v.y - lo);
    unsigned c = (unsigned)(v.z - lo), d = (unsigned)(v.w - lo);
    if (a < (unsigned)HRANGE) atomicAdd(&histo[a], 1);
    if (b < (unsigned)HRANGE) atomicAdd(&histo[b], 1);
    if (c < (unsigned)HRANGE) atomicAdd(&histo[c], 1);
    if (d < (unsigned)HRANGE) atomicAdd(&histo[d], 1);
  }
  __syncthreads();
  for (int j = t; j < HRANGE; j += 1024)
    cnt_slice[(size_t)slice * N_NODES + lo + j] = histo[j];
}

// ---------------------------------------------------------------- scan pass 1 (+ fused slice exclusive-prefix)
__global__ void k_scan_part(int* __restrict__ cnt_slice, int* __restrict__ cnt,
                            int* __restrict__ bsum) {
  int b = blockIdx.x, t = threadIdx.x;
  int base = b * 1024 + t * 4;
  int tot = 0;
#pragma unroll
  for (int j = 0; j < 4; ++j) {
    int i = base + j;
    if (i < N_NODES) {
      int run = 0;
#pragma unroll
      for (int s = 0; s < NSLICE; ++s) {
        int v = cnt_slice[(size_t)s * N_NODES + i];
        cnt_slice[(size_t)s * N_NODES + i] = run;   // exclusive prefix in place
        run += v;
      }
      cnt[i] = run;
      tot += run;
    }
  }
  __shared__ int red[256];
  red[t] = tot; __syncthreads();
  for (int w = 128; w; w >>= 1) { if (t < w) red[t] += red[t + w]; __syncthreads(); }
  if (t == 0) bsum[b] = red[0];
}

__global__ void k_scan_mid(const int* __restrict__ bsum, int* __restrict__ boff,
                           int* __restrict__ rowstart) {
  int t = threadIdx.x;
  __shared__ int sh[128];
  int own = (t < NB) ? bsum[t] : 0;
  sh[t] = own;
  __syncthreads();
  for (int off = 1; off < 128; off <<= 1) {
    int v = (t >= off) ? sh[t - off] : 0;
    __syncthreads();
    sh[t] += v;
    __syncthreads();
  }
  if (t < NB) boff[t] = sh[t] - own;
  if (t == NB - 1) rowstart[N_NODES] = sh[t];
}

__global__ void k_scan_fin(const int* __restrict__ cnt, const int* __restrict__ boff,
                           int* __restrict__ rowstart) {
  int b = blockIdx.x, t = threadIdx.x;
  int base = b * 1024 + t * 4;
  int v0 = 0, v1 = 0, v2 = 0, v3 = 0;
  if (base + 0 < N_NODES) v0 = cnt[base + 0];
  if (base + 1 < N_NODES) v1 = cnt[base + 1];
  if (base + 2 < N_NODES) v2 = cnt[base + 2];
  if (base + 3 < N_NODES) v3 = cnt[base + 3];
  int tsum = v0 + v1 + v2 + v3;
  __shared__ int sh[256];
  sh[t] = tsum;
  __syncthreads();
  for (int off = 1; off < 256; off <<= 1) {
    int v = (t >= off) ? sh[t - off] : 0;
    __syncthreads();
    sh[t] += v;
    __syncthreads();
  }
  int run = boff[b] + sh[t] - tsum;
  if (base + 0 < N_NODES) rowstart[base + 0] = run; run += v0;
  if (base + 1 < N_NODES) rowstart[base + 1] = run; run += v1;
  if (base + 2 < N_NODES) rowstart[base + 2] = run; run += v2;
  if (base + 3 < N_NODES) rowstart[base + 3] = run;
}

// ---------------------------------------------------------------- scatter via LDS cursor, 256 blocks
__launch_bounds__(1024)
__global__ void k_scatter_slice(const int* __restrict__ src, const int* __restrict__ dst,
                                const int* __restrict__ rowstart,
                                const int* __restrict__ cnt_slice, int* __restrict__ csr) {
  __shared__ int cur[HRANGE];
  int t = threadIdx.x;
  int range = blockIdx.x >> 5, slice = blockIdx.x & 31;
  int lo = range * HRANGE;
  for (int j = t; j < HRANGE; j += 1024)
    cur[j] = rowstart[lo + j] + cnt_slice[(size_t)slice * N_NODES + lo + j];
  __syncthreads();
  const int4* dp = (const int4*)(dst + slice * ESLICE);
  const int4* sp = (const int4*)(src + slice * ESLICE);
  for (int q = t; q < ESLICE / 4; q += 1024) {
    int4 d = dp[q];
    int4 s = sp[q];
    unsigned o;
    o = (unsigned)(d.x - lo); if (o < (unsigned)HRANGE) { int p = atomicAdd(&cur[o], 1); csr[p] = s.x; }
    o = (unsigned)(d.y - lo); if (o < (unsigned)HRANGE) { int p = atomicAdd(&cur[o], 1); csr[p] = s.y; }
    o = (unsigned)(d.z - lo); if (o < (unsigned)HRANGE) { int p = atomicAdd(&cur[o], 1); csr[p] = s.z; }
    o = (unsigned)(d.w - lo); if (o < (unsigned)HRANGE) { int p = atomicAdd(&cur[o], 1); csr[p] = s.w; }
  }
}

// ---------------------------------------------------------------- graph CSR starts
__global__ void k_starts_fill(const int* __restrict__ gid, int* __restrict__ starts) {
  int i = blockIdx.x * blockDim.x + threadIdx.x;
  if (i >= N_NODES) return;
  int gi = gid[i];
  if (i == 0) {
    for (int g = 0; g <= gi; ++g) starts[g] = 0;
  } else {
    int gp = gid[i - 1];
    if (gp != gi) for (int g = gp + 1; g <= gi; ++g) starts[g] = i;
  }
  if (i == N_NODES - 1) {
    for (int g = gi + 1; g <= NG; ++g) starts[g] = N_NODES;
  }
}

// ---------------------------------------------------------------- fused BN col stats + init_avg sums
__launch_bounds__(256)
__global__ void k_stats1(const float* __restrict__ x, const int* __restrict__ gid,
                         float* __restrict__ sums, float* __restrict__ initavg) {
  __shared__ float ls[8][DIM];
  __shared__ float ls2[8][DIM];
  __shared__ float lseg[4][8][DIM];
  int t = threadIdx.x;
  int col4 = (t & 31) * 4, rg = t >> 5;
  for (int i = t; i < 4 * 8 * DIM; i += 256) ((float*)lseg)[i] = 0.f;
  int base = blockIdx.x * SB;
  int rend = min(base + SB, N_NODES);
  int g0 = gid[base];
  int gl = gid[rend - 1];
  __syncthreads();
  float4 s = {0.f,0.f,0.f,0.f}, s2 = {0.f,0.f,0.f,0.f};
  float4 acc = {0.f,0.f,0.f,0.f};
  if (g0 == gl) {
    for (int r = base + rg; r < rend; r += 8) {
      float4 v = *(const float4*)&x[(size_t)r * DIM + col4];
      s.x += v.x; s.y += v.y; s.z += v.z; s.w += v.w;
      s2.x += v.x*v.x; s2.y += v.y*v.y; s2.z += v.z*v.z; s2.w += v.w*v.w;
      acc.x += v.x; acc.y += v.y; acc.z += v.z; acc.w += v.w;
    }
    lseg[0][rg][col4+0] = acc.x; lseg[0][rg][col4+1] = acc.y;
    lseg[0][rg][col4+2] = acc.z; lseg[0][rg][col4+3] = acc.w;
  } else {
    int curg = g0;
    for (int r = base + rg; r < rend; r += 8) {
      float4 v = *(const float4*)&x[(size_t)r * DIM + col4];
      s.x += v.x; s.y += v.y; s.z += v.z; s.w += v.w;
      s2.x += v.x*v.x; s2.y += v.y*v.y; s2.z += v.z*v.z; s2.w += v.w*v.w;
      int g = gid[r];
      if (g != curg) {
        int slot = curg - g0;
        if (slot < 4) {
          lseg[slot][rg][col4+0] = acc.x; lseg[slot][rg][col4+1] = acc.y;
          lseg[slot][rg][col4+2] = acc.z; lseg[slot][rg][col4+3] = acc.w;
        } else {
          atomicAdd(&initavg[curg * DIM + col4+0], acc.x);
          atomicAdd(&initavg[curg * DIM + col4+1], acc.y);
          atomicAdd(&initavg[curg * DIM + col4+2], acc.z);
          atomicAdd(&initavg[curg * DIM + col4+3], acc.w);
        }
        acc.x = acc.y = acc.z = acc.w = 0.f;
        curg = g;
      }
      acc.x += v.x; acc.y += v.y; acc.z += v.z; acc.w += v.w;
    }
    int slot = curg - g0;
    if (slot < 4) {
      lseg[slot][rg][col4+0] = acc.x; lseg[slot][rg][col4+1] = acc.y;
      lseg[slot][rg][col4+2] = acc.z; lseg[slot][rg][col4+3] = acc.w;
    } else {
      atomicAdd(&initavg[curg * DIM + col4+0], acc.x);
      atomicAdd(&initavg[curg * DIM + col4+1], acc.y);
      atomicAdd(&initavg[curg * DIM + col4+2], acc.z);
      atomicAdd(&initavg[curg * DIM + col4+3], acc.w);
    }
  }
  *(float4*)&ls[rg][col4] = s;
  *(float4*)&ls2[rg][col4] = s2;
  __syncthreads();
  if (t < DIM) {
    float a = 0.f, b = 0.f;
#pragma unroll
    for (int j = 0; j < 8; ++j) { a += ls[j][t]; b += ls2[j][t]; }
    atomicAdd(&sums[t], a);
    atomicAdd(&sums[DIM + t], b);
#pragma unroll
    for (int slot = 0; slot < 4; ++slot) {
      float v = 0.f;
#pragma unroll
      for (int j = 0; j < 8; ++j) v += lseg[slot][j][t];
      int g = g0 + slot;
      if (g < NG && v != 0.f) atomicAdd(&initavg[g * DIM + t], v);
    }
  }
}

__global__ void k_avg_div(const int* __restrict__ starts, float* __restrict__ outp) {
  int g = blockIdx.x, d = threadIdx.x;
  float cnt = fmaxf((float)(starts[g + 1] - starts[g]), 1.0f);
  outp[g * DIM + d] /= cnt;
}

// ---------------------------------------------------------------- layer-2 col sums from conv1 partials
__global__ void k_colred(const float* __restrict__ psum, const float* __restrict__ psq,
                         float* __restrict__ sums) {
  int c = blockIdx.x, t = threadIdx.x;
  __shared__ float r1[256], r2[256];
  float a = 0.f, b = 0.f;
  for (int j = t; j < NBLK_CONV; j += 256) {
    a += psum[(size_t)c * NBLK_CONV + j];
    b += psq[(size_t)c * NBLK_CONV + j];
  }
  r1[t] = a; r2[t] = b; __syncthreads();
  for (int w = 128; w; w >>= 1) { if (t < w) { r1[t] += r1[t + w]; r2[t] += r2[t + w]; } __syncthreads(); }
  if (t == 0) { sums[c] = r1[0]; sums[DIM + c] = r2[0]; }
}

// ---------------------------------------------------------------- xb = bf16(BN(x) * rsqrt(outdeg))
__launch_bounds__(256)
__global__ void k_bnx(const float* __restrict__ x, const float* __restrict__ sums,
                      const float* __restrict__ gamma, const float* __restrict__ beta,
                      const int* __restrict__ cntO, unsigned short* __restrict__ xb) {
  int idx = blockIdx.x * 256 + threadIdx.x;
  int row = idx >> 5, c4 = (idx & 31) * 4;
  float4 sm = *(const float4*)&sums[c4];
  float4 sq = *(const float4*)&sums[DIM + c4];
  float4 ga = *(const float4*)&gamma[c4];
  float4 be = *(const float4*)&beta[c4];
  const float inv = 1.0f / N_NODES;
  float4 sc, sh;
  {
    float m = sm.x * inv, va = sq.x * inv - m * m;
    sc.x = rsqrtf(fmaxf(va, 0.f) + BN_EPS) * ga.x; sh.x = be.x - m * sc.x;
    m = sm.y * inv; va = sq.y * inv - m * m;
    sc.y = rsqrtf(fmaxf(va, 0.f) + BN_EPS) * ga.y; sh.y = be.y - m * sc.y;
    m = sm.z * inv; va = sq.z * inv - m * m;
    sc.z = rsqrtf(fmaxf(va, 0.f) + BN_EPS) * ga.z; sh.z = be.z - m * sc.z;
    m = sm.w * inv; va = sq.w * inv - m * m;
    sc.w = rsqrtf(fmaxf(va, 0.f) + BN_EPS) * ga.w; sh.w = be.w - m * sc.w;
  }
  float4 v = *(const float4*)&x[(size_t)row * DIM + c4];
  float f = rsqrtf(fmaxf((float)cntO[row], 1.0f));
  ushort4 o;
  o.x = f2bf((v.x * sc.x + sh.x) * f);
  o.y = f2bf((v.y * sc.y + sh.y) * f);
  o.z = f2bf((v.z * sc.z + sh.z) * f);
  o.w = f2bf((v.w * sc.w + sh.w) * f);
  *(ushort4*)&xb[(size_t)row * DIM + c4] = o;
}

// ---------------------------------------------------------------- W -> bf16 transposed
__global__ void k_prepW(const float* __restrict__ W1, const float* __restrict__ W2,
                        unsigned short* __restrict__ WbT1, unsigned short* __restrict__ WbT2) {
  int idx = blockIdx.x * 256 + threadIdx.x;
  int which = idx >> 14;
  int i = idx & 16383;
  int k = i >> 7, c = i & 127;
  const float* W = which ? W2 : W1;
  unsigned short* O = which ? WbT2 : WbT1;
  O[c * DIM + k] = f2bf(W[k * DIM + c]);
}

// ---------------------------------------------------------------- pull-mode SpMM -> bf16 agg
__launch_bounds__(256, 8)
__global__ void k_spmm_pull(const unsigned short* __restrict__ xb, const int* __restrict__ csr,
                            const int* __restrict__ rowstart, unsigned short* __restrict__ aggb) {
  int row = blockIdx.x * 4 + threadIdx.y;
  int l = threadIdx.x;
  int half = l >> 5, l32 = l & 31;
  int s = rowstart[row], e = rowstart[row + 1];
  float4 acc = {0.f, 0.f, 0.f, 0.f};
  const size_t coff = (size_t)l32 * 4;
  int i = s + half;
  for (; i + 14 < e; i += 16) {        // 8 neighbors per half per iter
    int s0 = csr[i],      s1 = csr[i + 2],  s2 = csr[i + 4],  s3 = csr[i + 6];
    int s4 = csr[i + 8],  s5 = csr[i + 10], s6 = csr[i + 12], s7 = csr[i + 14];
    uint2 w0 = *(const uint2*)&xb[(size_t)s0 * DIM + coff];
    uint2 w1 = *(const uint2*)&xb[(size_t)s1 * DIM + coff];
    uint2 w2 = *(const uint2*)&xb[(size_t)s2 * DIM + coff];
    uint2 w3 = *(const uint2*)&xb[(size_t)s3 * DIM + coff];
    uint2 w4 = *(const uint2*)&xb[(size_t)s4 * DIM + coff];
    uint2 w5 = *(const uint2*)&xb[(size_t)s5 * DIM + coff];
    uint2 w6 = *(const uint2*)&xb[(size_t)s6 * DIM + coff];
    uint2 w7 = *(const uint2*)&xb[(size_t)s7 * DIM + coff];
    acc.x += (__uint_as_float(w0.x << 16) + __uint_as_float(w1.x << 16))
           + (__uint_as_float(w2.x << 16) + __uint_as_float(w3.x << 16))
           + (__uint_as_float(w4.x << 16) + __uint_as_float(w5.x << 16))
           + (__uint_as_float(w6.x << 16) + __uint_as_float(w7.x << 16));
    acc.y += (__uint_as_float(w0.x & 0xFFFF0000u) + __uint_as_float(w1.x & 0xFFFF0000u))
           + (__uint_as_float(w2.x & 0xFFFF0000u) + __uint_as_float(w3.x & 0xFFFF0000u))
           + (__uint_as_float(w4.x & 0xFFFF0000u) + __uint_as_float(w5.x & 0xFFFF0000u))
           + (__uint_as_float(w6.x & 0xFFFF0000u) + __uint_as_float(w7.x & 0xFFFF0000u));
    acc.z += (__uint_as_float(w0.y << 16) + __uint_as_float(w1.y << 16))
           + (__uint_as_float(w2.y << 16) + __uint_as_float(w3.y << 16))
           + (__uint_as_float(w4.y << 16) + __uint_as_float(w5.y << 16))
           + (__uint_as_float(w6.y << 16) + __uint_as_float(w7.y << 16));
    acc.w += (__uint_as_float(w0.y & 0xFFFF0000u) + __uint_as_float(w1.y & 0xFFFF0000u))
           + (__uint_as_float(w2.y & 0xFFFF0000u) + __uint_as_float(w3.y & 0xFFFF0000u))
           + (__uint_as_float(w4.y & 0xFFFF0000u) + __uint_as_float(w5.y & 0xFFFF0000u))
           + (__uint_as_float(w6.y & 0xFFFF0000u) + __uint_as_float(w7.y & 0xFFFF0000u));
  }
  for (; i + 6 < e; i += 8) {
    int s0 = csr[i], s1 = csr[i + 2], s2 = csr[i + 4], s3 = csr[i + 6];
    uint2 w0 = *(const uint2*)&xb[(size_t)s0 * DIM + coff];
    uint2 w1 = *(const uint2*)&xb[(size_t)s1 * DIM + coff];
    uint2 w2 = *(const uint2*)&xb[(size_t)s2 * DIM + coff];
    uint2 w3 = *(const uint2*)&xb[(size_t)s3 * DIM + coff];
    acc.x += __uint_as_float(w0.x << 16) + __uint_as_float(w1.x << 16)
           + __uint_as_float(w2.x << 16) + __uint_as_float(w3.x << 16);
    acc.y += __uint_as_float(w0.x & 0xFFFF0000u) + __uint_as_float(w1.x & 0xFFFF0000u)
           + __uint_as_float(w2.x & 0xFFFF0000u) + __uint_as_float(w3.x & 0xFFFF0000u);
    acc.z += __uint_as_float(w0.y << 16) + __uint_as_float(w1.y << 16)
           + __uint_as_float(w2.y << 16) + __uint_as_float(w3.y << 16);
    acc.w += __uint_as_float(w0.y & 0xFFFF0000u) + __uint_as_float(w1.y & 0xFFFF0000u)
           + __uint_as_float(w2.y & 0xFFFF0000u) + __uint_as_float(w3.y & 0xFFFF0000u);
  }
  for (; i < e; i += 2) {
    int s0 = csr[i];
    uint2 w0 = *(const uint2*)&xb[(size_t)s0 * DIM + coff];
    acc.x += __uint_as_float(w0.x << 16);
    acc.y += __uint_as_float(w0.x & 0xFFFF0000u);
    acc.z += __uint_as_float(w0.y << 16);
    acc.w += __uint_as_float(w0.y & 0xFFFF0000u);
  }
  acc.x += __shfl_xor(acc.x, 32);
  acc.y += __shfl_xor(acc.y, 32);
  acc.z += __shfl_xor(acc.z, 32);
  acc.w += __shfl_xor(acc.w, 32);
  if (half == 0) {
    float isi = rsqrtf(fmaxf((float)(e - s), 1.0f));
    ushort4 o;
    o.x = f2bf(acc.x * isi);
    o.y = f2bf(acc.y * isi);
    o.z = f2bf(acc.z * isi);
    o.w = f2bf(acc.w * isi);
    *(ushort4*)&aggb[(size_t)row * DIM + l32 * 4] = o;
  }
}

// ---------------------------------------------------------------- MFMA conv (+ optional gate, + optional column-stat partials)
__launch_bounds__(256)
__global__ void k_conv(const unsigned short* __restrict__ aggb,
                       const unsigned short* __restrict__ WbT,
                       const float* __restrict__ bias, const float* __restrict__ hres,
                       float* __restrict__ outp,
                       const float* __restrict__ gWp, const float* __restrict__ gbp,
                       float* __restrict__ gatep,
                       float* __restrict__ psum, float* __restrict__ psq) {
  __shared__ unsigned short As[64 * 136];
  __shared__ unsigned short Ws[128 * 136];
  __shared__ float gsh[64];
  float* Of = (float*)Ws;
  int t = threadIdx.x;
  int row0 = blockIdx.x * 64;

  if (gatep && t < 64) gsh[t] = 0.f;

  for (int i = t; i < 1024; i += 256) {
    int r = i >> 4, q = i & 15;
    int row = row0 + r;
    int4 v = {0, 0, 0, 0};
    if (row < N_NODES) v = *(const int4*)&aggb[(size_t)row * DIM + q * 8];
    *(int4*)&As[r * 136 + q * 8] = v;
  }
  for (int i = t; i < 2048; i += 256) {
    int c = i >> 4, q = i & 15;
    *(int4*)&Ws[c * 136 + q * 8] = *(const int4*)&WbT[(size_t)c * DIM + q * 8];
  }
  __syncthreads();

  int wid = t >> 6, l = t & 63;
  int wr = wid >> 1, wc = wid & 1;
  int lr = l & 15, lq = l >> 4;
  f32x4 acc[2][4] = {};
  const unsigned short* Ab = &As[(wr * 32 + lr) * 136 + lq * 8];
  const unsigned short* Bb = &Ws[(wc * 64 + lr) * 136 + lq * 8];
#pragma unroll
  for (int kk = 0; kk < 4; ++kk) {
    bf16x8 a0 = *(const bf16x8*)(Ab + kk * 32);
    bf16x8 a1 = *(const bf16x8*)(Ab + 16 * 136 + kk * 32);
    bf16x8 b0 = *(const bf16x8*)(Bb + kk * 32);
    bf16x8 b1 = *(const bf16x8*)(Bb + 16 * 136 + kk * 32);
    bf16x8 b2 = *(const bf16x8*)(Bb + 32 * 136 + kk * 32);
    bf16x8 b3 = *(const bf16x8*)(Bb + 48 * 136 + kk * 32);
    acc[0][0] = __builtin_amdgcn_mfma_f32_16x16x32_bf16(a0, b0, acc[0][0], 0, 0, 0);
    acc[0][1] = __builtin_amdgcn_mfma_f32_16x16x32_bf16(a0, b1, acc[0][1], 0, 0, 0);
    acc[0][2] = __builtin_amdgcn_mfma_f32_16x16x32_bf16(a0, b2, acc[0][2], 0, 0, 0);
    acc[0][3] = __builtin_amdgcn_mfma_f32_16x16x32_bf16(a0, b3, acc[0][3], 0, 0, 0);
    acc[1][0] = __builtin_amdgcn_mfma_f32_16x16x32_bf16(a1, b0, acc[1][0], 0, 0, 0);
    acc[1][1] = __builtin_amdgcn_mfma_f32_16x16x32_bf16(a1, b1, acc[1][1], 0, 0, 0);
    acc[1][2] = __builtin_amdgcn_mfma_f32_16x16x32_bf16(a1, b2, acc[1][2], 0, 0, 0);
    acc[1][3] = __builtin_amdgcn_mfma_f32_16x16x32_bf16(a1, b3, acc[1][3], 0, 0, 0);
  }
  __syncthreads();

#pragma unroll
  for (int rt = 0; rt < 2; ++rt) {
#pragma unroll
    for (int ct = 0; ct < 4; ++ct) {
      int rr = wr * 32 + rt * 16 + lq * 4;
      int cc = wc * 64 + ct * 16 + lr;
#pragma unroll
      for (int i = 0; i < 4; ++i)
        Of[(rr + i) * 132 + cc] = acc[rt][ct][i];
    }
  }
  __syncthreads();

  float st[4] = {0.f, 0.f, 0.f, 0.f}, st2[4] = {0.f, 0.f, 0.f, 0.f};
#pragma unroll
  for (int i = 0; i < 8; ++i) {
    int fi = t + i * 256;
    int r = fi >> 5, c4 = (fi & 31) * 4;
    int row = row0 + r;
    if (row < N_NODES) {
      float4 o  = *(float4*)&Of[r * 132 + c4];
      float4 bv = *(const float4*)&bias[c4];
      float4 hv = *(const float4*)&hres[(size_t)row * DIM + c4];
      float4 y = {hv.x + fmaxf(o.x + bv.x, 0.f), hv.y + fmaxf(o.y + bv.y, 0.f),
                  hv.z + fmaxf(o.z + bv.z, 0.f), hv.w + fmaxf(o.w + bv.w, 0.f)};
      *(float4*)&outp[(size_t)row * DIM + c4] = y;
      if (gatep) {
        float4 gw = *(const float4*)&gWp[c4];
        atomicAdd(&gsh[r], y.x * gw.x + y.y * gw.y + y.z * gw.z + y.w * gw.w);
      }
      if (psum) {
        st[0] += y.x; st[1] += y.y; st[2] += y.z; st[3] += y.w;
        st2[0] += y.x*y.x; st2[1] += y.y*y.y; st2[2] += y.z*y.z; st2[3] += y.w*y.w;
      }
    }
  }
  if (gatep) {
    __syncthreads();
    int row = row0 + t;
    if (t < 64 && row < N_NODES) gatep[row] = gsh[t] + gbp[0];
  }
  if (psum) {
    float* sls  = (float*)As;
    float* sls2 = sls + 8 * DIM;
    int rg = t >> 5, c4 = (t & 31) * 4;
    __syncthreads();
#pragma unroll
    for (int i = 0; i < 4; ++i) {
      sls[rg * DIM + c4 + i]  = st[i];
      sls2[rg * DIM + c4 + i] = st2[i];
    }
    __syncthreads();
    if (t < DIM) {
      float a = 0.f, b = 0.f;
#pragma unroll
      for (int j = 0; j < 8; ++j) { a += sls[j * DIM + t]; b += sls2[j * DIM + t]; }
      psum[(size_t)t * NBLK_CONV + blockIdx.x] = a;
      psq[(size_t)t * NBLK_CONV + blockIdx.x]  = b;
    }
  }
}

// ---------------------------------------------------------------- per-graph softmax stats
__global__ void k_gstats(const float* __restrict__ gate, const int* __restrict__ starts,
                         float* __restrict__ gmax, float* __restrict__ gden) {
  int g = blockIdx.x;
  int s = starts[g], e = starts[g + 1];
  int t = threadIdx.x;
  __shared__ float red[256];
  float m = -INFINITY;
  for (int i = s + t; i < e; i += 256) m = fmaxf(m, gate[i]);
  red[t] = m; __syncthreads();
  for (int w = 128; w; w >>= 1) { if (t < w) red[t] = fmaxf(red[t], red[t + w]); __syncthreads(); }
  float mg = red[0]; __syncthreads();
  float ssum = 0.f;
  for (int i = s + t; i < e; i += 256) ssum += expf(gate[i] - mg);
  red[t] = ssum; __syncthreads();
  for (int w = 128; w; w >>= 1) { if (t < w) red[t] += red[t + w]; __syncthreads(); }
  if (t == 0) { gmax[g] = mg; gden[g] = red[0]; }
}

// ---------------------------------------------------------------- weighted pooling (2048 blocks, float4, LDS reduce)
__launch_bounds__(256)
__global__ void k_pool(const float* __restrict__ h2, const float* __restrict__ gate,
                       const int* __restrict__ starts, const float* __restrict__ gmax,
                       const float* __restrict__ gden, float* __restrict__ outp) {
  __shared__ float ls[8][DIM];
  int g = blockIdx.x >> 5, part = blockIdx.x & 31;
  int s = starts[g], e = starts[g + 1];
  int t = threadIdx.x;
  int col4 = (t & 31) * 4, rg = t >> 5;
  float mg = gmax[g];
  float dn = gden[g];
  float invden = dn > 0.f ? 1.0f / dn : 0.f;
  float4 acc = {0.f, 0.f, 0.f, 0.f};
  for (int i = s + part + rg * 32; i < e; i += 256) {
    float w = expf(gate[i] - mg) * invden;
    float4 v = *(const float4*)&h2[(size_t)i * DIM + col4];
    acc.x += w * v.x; acc.y += w * v.y; acc.z += w * v.z; acc.w += w * v.w;
  }
  *(float4*)&ls[rg][col4] = acc;
  __syncthreads();
  if (t < DIM) {
    float a = 0.f;
#pragma unroll
    for (int j = 0; j < 8; ++j) a += ls[j][t];
    if (a != 0.f) atomicAdd(&outp[g * DIM + t], a);
  }
}

// ---------------------------------------------------------------- launch
extern "C" void kernel_launch(void* const* d_in, const int* in_sizes, int n_in,
                              void* d_out, int out_size, void* d_ws, size_t ws_size,
                              hipStream_t stream) {
  const float* h    = (const float*)d_in[0];
  const int*   src  = (const int*)d_in[1];
  const int*   dst  = (const int*)d_in[2];
  const int*   gid  = (const int*)d_in[3];
  const float* W1   = (const float*)d_in[5];
  const float* b1   = (const float*)d_in[6];
  const float* W2   = (const float*)d_in[7];
  const float* b2   = (const float*)d_in[8];
  const float* gW   = (const float*)d_in[9];
  const float* gb   = (const float*)d_in[10];
  const float* gamma= (const float*)d_in[11];
  const float* beta = (const float*)d_in[12];
  float* out = (float*)d_out;

  char* ws = (char*)d_ws;
  float* h12     = (float*)ws; ws += (size_t)N_NODES * DIM * 4;
  unsigned short* xb   = (unsigned short*)ws; ws += (size_t)N_NODES * DIM * 2;
  unsigned short* aggb = (unsigned short*)ws; ws += (size_t)N_NODES * DIM * 2;
  int*   csr     = (int*)ws;   ws += (size_t)N_EDGES * 4;
  int*   cnt_slice = (int*)ws; ws += (size_t)NSLICE * N_NODES * 4;
  float* psum    = (float*)ws; ws += (size_t)DIM * NBLK_CONV * 4;
  float* psq     = (float*)ws; ws += (size_t)DIM * NBLK_CONV * 4;
  unsigned short* WbT1 = (unsigned short*)ws; ws += DIM * DIM * 2;
  unsigned short* WbT2 = (unsigned short*)ws; ws += DIM * DIM * 2;
  int*   rowstart= (int*)ws;   ws += (N_NODES + 1) * 4;
  int*   cnt     = (int*)ws;   ws += N_NODES * 4;
  int*   cntO    = (int*)ws;   ws += N_NODES * 4;
  float* gate    = (float*)ws; ws += N_NODES * 4;
  float* sums    = (float*)ws; ws += 2 * DIM * 4;
  float* gmax    = (float*)ws; ws += NG * 4;
  float* gden    = (float*)ws; ws += NG * 4;
  int*   starts  = (int*)ws;   ws += (NG + 1) * 4;
  int*   bsum    = (int*)ws;   ws += NB * 4;
  int*   boff    = (int*)ws;   ws += NB * 4;

  hipMemsetAsync(cntO,  0, N_NODES * 4, stream);
  hipMemsetAsync(sums,  0, 2 * DIM * 4, stream);
  hipMemsetAsync(d_out, 0, (size_t)out_size * 4, stream);

  // graph structure
  k_histO<<<256, 1024, 0, stream>>>(src, cntO);
  k_histD<<<256, 1024, 0, stream>>>(dst, cnt_slice);
  k_scan_part<<<NB, 256, 0, stream>>>(cnt_slice, cnt, bsum);
  k_scan_mid<<<1, 128, 0, stream>>>(bsum, boff, rowstart);
  k_scan_fin<<<NB, 256, 0, stream>>>(cnt, boff, rowstart);
  k_scatter_slice<<<256, 1024, 0, stream>>>(src, dst, rowstart, cnt_slice, csr);
  k_starts_fill<<<(N_NODES + 255) / 256, 256, 0, stream>>>(gid, starts);
  k_prepW<<<128, 256, 0, stream>>>(W1, W2, WbT1, WbT2);

  // layer 1 (stats fused with init_avg accumulation)
  k_stats1<<<NSB, 256, 0, stream>>>(h, gid, sums, out + NG * DIM);
  k_avg_div<<<NG, DIM, 0, stream>>>(starts, out + NG * DIM);
  k_bnx<<<N_NODES * 32 / 256, 256, 0, stream>>>(h, sums, gamma, beta, cntO, xb);
  k_spmm_pull<<<N_NODES / 4, dim3(64, 4), 0, stream>>>(xb, csr, rowstart, aggb);
  k_conv<<<NBLK_CONV, 256, 0, stream>>>(aggb, WbT1, b1, h, h12,
                                        nullptr, nullptr, nullptr, psum, psq);

  // layer 2 (stats from conv1 partials)
  k_colred<<<DIM, 256, 0, stream>>>(psum, psq, sums);
  k_bnx<<<N_NODES * 32 / 256, 256, 0, stream>>>(h12, sums, gamma, beta, cntO, xb);
  k_spmm_pull<<<N_NODES / 4, dim3(64, 4), 0, stream>>>(xb, csr, rowstart, aggb);
  k_conv<<<NBLK_CONV, 256, 0, stream>>>(aggb, WbT2, b2, h12, h12,
                                        gW, gb, gate, nullptr, nullptr);

  // pooling
  k_gstats<<<NG, 256, 0, stream>>>(gate, starts, gmax, gden);
  k_pool<<<NG * 32, 256, 0, stream>>>(h12, gate, starts, gmax, gden, out);
}